// Round 4
// baseline (229.158 us; speedup 1.0000x reference)
//
#include <hip/hip_runtime.h>
#include <math.h>

// PCEN: x[B=64, C=128, T=4000] fp32.
// smooth[0]=x[0]; smooth[t]=(1-s)*smooth[t-1]+s*x[t], s=0.025
// out = sqrt(x/(smooth+1e-6)^0.98 + 2) - sqrt(2)
//
// R4: one wave per channel (R3 layout: lane l owns float4 chunks l+64k),
// SOFTWARE-PIPELINED in 4 groups of 4 segment-columns. R0-R3 falsified
// VALU-issue, MLP, and barrier theories (dur pinned at 79-82us with all
// pipes <35% busy). Remaining suspect: burst-then-stall phases — R3's
// B-loop consumed all 16 loads at once (effective vmcnt(0) at the top),
// serializing a device-wide read burst, a dead compute phase, and a store
// burst. Here group g's compute runs while groups g+1,g+2's loads are in
// flight (compiler emits counted vmcnt stages at first use), so memory
// streams continuously under compute and waves desynchronize.
// Math unchanged from R3 (verified): literal per-step scan coefficients,
// (1-s)^256 segment compose, per-lane (1-s)^(4*lane) via one v_exp_f32.

constexpr int   TLEN = 4000;
constexpr int   NF4  = 1000;   // float4 chunks per channel
constexpr int   NTH  = 256;    // 4 independent waves = 4 channels per block
constexpr int   KPL  = 16;     // chunks per lane (64*16 = 1024 >= 1000)
constexpr int   G    = 4;      // segment-columns per pipeline group
constexpr int   NG   = KPL / G;
constexpr float S_C  = 0.025f;
constexpr float A_1  = 1.0f - S_C;

constexpr float fpow(float b, int n) {
    float r = 1.0f;
    for (int i = 0; i < n; ++i) r *= b;
    return r;
}
constexpr float A_2  = fpow(A_1, 2);
constexpr float A_3  = fpow(A_1, 3);
constexpr float A256 = fpow(A_1, 256);   // one segment = 64 lanes * 4 elems

// 4*log2(1-s): per-lane exclusive coefficient is exp2(lane * L2A4)
constexpr float L2A4 = -0.14610359f;

constexpr float ALPHA = 0.98f;
constexpr float EPS_C = 1e-6f;
constexpr float SQRT2 = 1.41421356237309515f;

__device__ __forceinline__ float pcen_elem(float x, float sm) {
    float t = sm + EPS_C;
    float p = __builtin_amdgcn_exp2f(-ALPHA * __builtin_amdgcn_logf(t)); // t^-alpha
    float y = fmaf(x, p, 2.0f);
    return __builtin_amdgcn_sqrtf(y) - SQRT2;
}

__global__ __launch_bounds__(NTH) void pcen_kernel(const float* __restrict__ x,
                                                   float* __restrict__ out,
                                                   int nch) {
    const int lane = threadIdx.x & 63;
    const int ch   = blockIdx.x * (NTH / 64) + (threadIdx.x >> 6);
    if (ch >= nch) return;

    const size_t base = (size_t)ch * TLEN;
    const float4* __restrict__ x4 = (const float4*)(x + base);
    float4*       __restrict__ o4 = (float4*)(out + base);

    float4 v[KPL];
    float  B[KPL];

    // ---- prologue: issue loads for groups 0 and 1 (8 float4s in flight) ----
#pragma unroll
    for (int k = 0; k < 2 * G; ++k) {
        int f4 = lane + 64 * k;
        v[k] = (f4 < NF4) ? x4[f4] : make_float4(0.f, 0.f, 0.f, 0.f);
    }

    constexpr float CD[6] = { fpow(A_1, 4),  fpow(A_1, 8),  fpow(A_1, 16),
                              fpow(A_1, 32), fpow(A_1, 64), fpow(A_1, 128) };

    // per-lane exclusive coefficient A_1^(4*lane)
    const float Al = __builtin_amdgcn_exp2f((float)lane * L2A4);

    float e = 0.0f;   // smoothed value entering current segment (wave-uniform)

#pragma unroll
    for (int g = 0; g < NG; ++g) {
        // ---- prefetch group g+2 while computing group g ----
        if (g + 2 < NG) {
#pragma unroll
            for (int j = 0; j < G; ++j) {
                int k  = (g + 2) * G + j;
                int f4 = lane + 64 * k;
                v[k] = (f4 < NF4) ? x4[f4] : make_float4(0.f, 0.f, 0.f, 0.f);
            }
        }

        // ---- per-chunk offset B for this group (coefficient = A_1^4) ----
        // B = A_1^3*b0 + s*(A_1^2*x1 + A_1*x2 + x3); b0 = s*x0 (x0 at t=0)
#pragma unroll
        for (int j = 0; j < G; ++j) {
            const int k = g * G + j;
            float4 r  = v[k];
            float  b0 = (lane == 0 && k == 0) ? r.x : S_C * r.x;
            B[k] = fmaf(A_3, b0, S_C * fmaf(A_2, r.y, fmaf(A_1, r.z, r.w)));
        }

        // ---- inclusive wave scan, 6 shuffle steps x G independent columns ----
#pragma unroll
        for (int s = 0; s < 6; ++s) {
            const int   d  = 1 << s;
            const float cc = CD[s];
            float Bp[G];
#pragma unroll
            for (int j = 0; j < G; ++j) Bp[j] = __shfl_up(B[g * G + j], d);
            const bool ok = (lane >= d);
#pragma unroll
            for (int j = 0; j < G; ++j) {
                const int k = g * G + j;
                B[k] = fmaf(cc, ok ? Bp[j] : 0.0f, B[k]);
            }
        }

        // ---- epilogue per column: exclusive shuffle, replay, pcen, store ----
#pragma unroll
        for (int j = 0; j < G; ++j) {
            const int k  = g * G + j;
            float Tk = (k < KPL - 1) ? __shfl(B[k], 63) : 0.0f;  // segment total
            float Bi = __shfl_up(B[k], 1);
            if (lane == 0) Bi = 0.0f;
            float sm = fmaf(Al, e, Bi);          // smoothed value entering chunk

            float4 r  = v[k];
            float  b0 = (lane == 0 && k == 0) ? r.x : S_C * r.x;
            float  s0 = fmaf(A_1, sm, b0);
            float  s1 = fmaf(A_1, s0, S_C * r.y);
            float  s2 = fmaf(A_1, s1, S_C * r.z);
            float  s3 = fmaf(A_1, s2, S_C * r.w);

            float4 o;
            o.x = pcen_elem(r.x, s0);
            o.y = pcen_elem(r.y, s1);
            o.z = pcen_elem(r.z, s2);
            o.w = pcen_elem(r.w, s3);

            int f4 = lane + 64 * k;
            if (f4 < NF4) o4[f4] = o;

            e = fmaf(A256, e, Tk);               // advance to next segment
        }
    }
}

extern "C" void kernel_launch(void* const* d_in, const int* in_sizes, int n_in,
                              void* d_out, int out_size, void* d_ws, size_t ws_size,
                              hipStream_t stream) {
    const float* x   = (const float*)d_in[0];
    float*       out = (float*)d_out;
    const int nch    = in_sizes[0] / TLEN;               // 8192 channels
    const int wpb    = NTH / 64;                         // 4 channels per block
    const int grid   = (nch + wpb - 1) / wpb;            // 2048 blocks
    pcen_kernel<<<grid, NTH, 0, stream>>>(x, out, nch);
}